// Round 2
// baseline (975.567 us; speedup 1.0000x reference)
//
#include <hip/hip_runtime.h>

// CoAttention: B=64, H=768, T=384. out (64,384,2304) fp32.
// ws layout (bytes), aliasing (Qhi/Qlo dead after gemm2 -> AQt/ADt):
//   Qhi bf16 (64,384,768)  @ 0           37,748,736   later: AQt bf16 (64,384,384) @ 0
//   Qlo bf16 (64,384,768)  @ 37748736    37,748,736   later: ADt bf16 (64,384,384) @ 37748736
//   M4  bf16 (64,1536,384) @ 75497472    75,497,472   rows 0..767 Qact^T, 768..1535 C_Q
//   Dt  bf16 (64,768,384)  @ 150994944   37,748,736
//   L   f32  (64,384,384)  @ 188743680   37,748,736   (first 2.36MB also used as Whi/Wlo
//                                                      scratch, dead once gemm2 writes L)
// out-as-scratch: out cols 0..1535 are free until gemm4. Per row (b,r), 6144 bytes:
//   [XQhi row | XQlo row | XDhi row | XDlo row]  (4 x 1536 B), written by splitX,
//   read by gemm1 (XQ) / gemm2 (XD), overwritten by gemm4.

typedef __bf16 bf16x8 __attribute__((ext_vector_type(8)));
typedef __bf16 bf16x4 __attribute__((ext_vector_type(4)));
typedef float  f32x4  __attribute__((ext_vector_type(4)));

#define HH 768
#define TT 384
#define OROWB 9216  // out row bytes (2304 f32)
#define XQHI 0
#define XQLO 1536
#define XDHI 3072
#define XDLO 4608

__device__ inline void split8(const float* __restrict__ p, bf16x8& hi, bf16x8& lo) {
    float4 f0 = *(const float4*)p;
    float4 f1 = *(const float4*)(p + 4);
    float f[8] = {f0.x, f0.y, f0.z, f0.w, f1.x, f1.y, f1.z, f1.w};
#pragma unroll
    for (int i = 0; i < 8; i++) {
        __bf16 h = (__bf16)f[i];
        hi[i] = h;
        lo[i] = (__bf16)(f[i] - (float)h);
    }
}

// async global->LDS, 16B per lane; LDS side must be wave-uniform base + lane*16
__device__ inline void gload16(const void* g, void* l) {
    __builtin_amdgcn_global_load_lds(
        (const __attribute__((address_space(1))) unsigned int*)g,
        (__attribute__((address_space(3))) unsigned int*)l, 16, 0, 0);
}

// ---- prep: Dt[b][h][s] = bf16(D[b][s][h]);  out[b][s][1536+h] = D[b][s][h] ----
// (round-0 structure: transpose + f32 copy only, no split work)
__global__ void prep_kernel(const float* __restrict__ x, __bf16* __restrict__ Dt,
                            float* __restrict__ out) {
    __shared__ float tile[32][33];
    int b = blockIdx.z;
    int h0 = blockIdx.x * 32, s0 = blockIdx.y * 32;
    int tx = threadIdx.x, ty = threadIdx.y;
    const float* src = x + ((size_t)b * HH + TT) * HH;  // D rows
    float* outb = out + (size_t)b * TT * 2304;
#pragma unroll
    for (int j = 0; j < 4; j++) {
        int s = s0 + ty + 8 * j, h = h0 + tx;
        float v = src[(size_t)s * HH + h];
        tile[ty + 8 * j][tx] = v;
        outb[(size_t)s * 2304 + 1536 + h] = v;
    }
    __syncthreads();
    __bf16* Dtb = Dt + (size_t)b * HH * TT;
#pragma unroll
    for (int j = 0; j < 4; j++) {
        int h = h0 + ty + 8 * j, s = s0 + tx;
        Dtb[(size_t)h * TT + s] = (__bf16)tile[tx][ty + 8 * j];
    }
}

// ---- splitX: vectorized hi/lo split of Q and D rows into out-scratch,
//      plus Whi/Wlo (blocks 9216..9503; boundary is block-aligned, no divergence) ----
__global__ void splitX_kernel(const float* __restrict__ x, const float* __restrict__ W,
                              float* __restrict__ out, __bf16* __restrict__ Whi,
                              __bf16* __restrict__ Wlo) {
    int idx = blockIdx.x * 256 + threadIdx.x;
    const int NX = 64 * 384 * 96;  // = 2359296, block-aligned (9216 blocks)
    if (idx < NX) {
        int hb = idx % 96;
        int s = (idx / 96) % 384;
        int b = idx / (96 * 384);
        const float* srcQ = x + (size_t)b * HH * HH + (size_t)s * HH + hb * 8;
        const float* srcD = srcQ + (size_t)TT * HH;
        char* scr = (char*)(out + (size_t)b * TT * 2304) + (size_t)s * OROWB + hb * 16;
        bf16x8 h, l;
        split8(srcQ, h, l);
        *(bf16x8*)(scr + XQHI) = h;
        *(bf16x8*)(scr + XQLO) = l;
        split8(srcD, h, l);
        *(bf16x8*)(scr + XDHI) = h;
        *(bf16x8*)(scr + XDLO) = l;
    } else {
        int wi = idx - NX;  // 0..73727 covers 768*768/8
        bf16x8 h, l;
        split8(W + (size_t)wi * 8, h, l);
        *(bf16x8*)&Whi[(size_t)wi * 8] = h;
        *(bf16x8*)&Wlo[(size_t)wi * 8] = l;
    }
}

// ---- gemm1: Qact = tanh(xQ @ W^T + b), split-precision (3 MFMA), 128x128 tile,
//      pure global_load_lds staging from pre-split XQ/W ----
__global__ __launch_bounds__(256) void gemm1_kernel(
    const float* __restrict__ outscr, const __bf16* __restrict__ Whi,
    const __bf16* __restrict__ Wlo, const float* __restrict__ bias,
    __bf16* __restrict__ Qhi, __bf16* __restrict__ Qlo, __bf16* __restrict__ M4) {
    __shared__ __bf16 Ah[128 * 32], Al[128 * 32], Bh[128 * 32], Bl[128 * 32];
    const int b = blockIdx.z;
    const int m_blk = blockIdx.y * 128, n_blk = blockIdx.x * 128;
    const int tid = threadIdx.x, lane = tid & 63, wave = tid >> 6;
    const int wm = wave >> 1, wn = wave & 1;
    const int r15 = lane & 15, quad = lane >> 4;
    const char* scr = (const char*)(outscr + (size_t)b * TT * 2304);
    f32x4 acc[4][4];
#pragma unroll
    for (int i = 0; i < 4; i++)
#pragma unroll
        for (int j = 0; j < 4; j++) acc[i][j] = (f32x4){0.f, 0.f, 0.f, 0.f};

    for (int k0 = 0; k0 < HH; k0 += 32) {
#pragma unroll
        for (int it = 0; it < 2; it++) {
            int c = it * 256 + tid;
            int r = c >> 2, q = c & 3;
            const char* arow = scr + (size_t)(m_blk + r) * OROWB + (size_t)(k0 + q * 8) * 2;
            gload16(arow + XQHI, &Ah[c * 8]);
            gload16(arow + XQLO, &Al[c * 8]);
            gload16(Whi + (size_t)(n_blk + r) * HH + k0 + q * 8, &Bh[c * 8]);
            gload16(Wlo + (size_t)(n_blk + r) * HH + k0 + q * 8, &Bl[c * 8]);
        }
        __syncthreads();
        bf16x8 ah[4], al[4], bh[4], bl[4];
#pragma unroll
        for (int i = 0; i < 4; i++) {
            int ra = (wm * 64 + i * 16 + r15) * 32 + quad * 8;
            ah[i] = *(const bf16x8*)&Ah[ra];
            al[i] = *(const bf16x8*)&Al[ra];
            int rb = (wn * 64 + i * 16 + r15) * 32 + quad * 8;
            bh[i] = *(const bf16x8*)&Bh[rb];
            bl[i] = *(const bf16x8*)&Bl[rb];
        }
#pragma unroll
        for (int i = 0; i < 4; i++)
#pragma unroll
            for (int j = 0; j < 4; j++) {
                acc[i][j] = __builtin_amdgcn_mfma_f32_16x16x32_bf16(ah[i], bh[j], acc[i][j], 0, 0, 0);
                acc[i][j] = __builtin_amdgcn_mfma_f32_16x16x32_bf16(ah[i], bl[j], acc[i][j], 0, 0, 0);
                acc[i][j] = __builtin_amdgcn_mfma_f32_16x16x32_bf16(al[i], bh[j], acc[i][j], 0, 0, 0);
            }
        __syncthreads();
    }
    __bf16* Qh = Qhi + (size_t)b * TT * HH;
    __bf16* Ql = Qlo + (size_t)b * TT * HH;
    __bf16* Mb = M4 + (size_t)b * 1536 * TT;
#pragma unroll
    for (int j = 0; j < 4; j++) {
        int col = n_blk + wn * 64 + j * 16 + r15;  // o
        float bv = bias[col];
#pragma unroll
        for (int i = 0; i < 4; i++) {
            int row0 = m_blk + wm * 64 + i * 16 + quad * 4;  // t
            bf16x4 mrow;
#pragma unroll
            for (int r = 0; r < 4; r++) {
                float v = tanhf(acc[i][j][r] + bv);
                __bf16 qh = (__bf16)v;
                Qh[(size_t)(row0 + r) * HH + col] = qh;
                Ql[(size_t)(row0 + r) * HH + col] = (__bf16)(v - (float)qh);
                mrow[r] = qh;
            }
            *(bf16x4*)&Mb[(size_t)col * TT + row0] = mrow;
        }
    }
}

// ---- gemm2: L[t][s] = sum_h Qact[t][h]*D[s][h], split-precision,
//      BM=64 x BN=128 tiles (grid 3x6x64 = 1152 blocks, 4.5/CU balance) ----
__global__ __launch_bounds__(256) void gemm2_kernel(
    const __bf16* __restrict__ Qhi, const __bf16* __restrict__ Qlo,
    const float* __restrict__ outscr, float* __restrict__ L) {
    __shared__ __bf16 Ah[64 * 32], Al[64 * 32], Bh[128 * 32], Bl[128 * 32];
    const int b = blockIdx.z;
    const int m_blk = blockIdx.y * 64, n_blk = blockIdx.x * 128;
    const int tid = threadIdx.x, lane = tid & 63, wave = tid >> 6;
    const int wm = wave >> 1, wn = wave & 1;
    const int r15 = lane & 15, quad = lane >> 4;
    const __bf16* Qh = Qhi + (size_t)b * TT * HH;
    const __bf16* Ql = Qlo + (size_t)b * TT * HH;
    const char* scr = (const char*)(outscr + (size_t)b * TT * 2304);
    f32x4 acc[2][4];
#pragma unroll
    for (int i = 0; i < 2; i++)
#pragma unroll
        for (int j = 0; j < 4; j++) acc[i][j] = (f32x4){0.f, 0.f, 0.f, 0.f};

    for (int k0 = 0; k0 < HH; k0 += 32) {
        {   // A-tile (64x32): one 256-thread pass per array
            int r = tid >> 2, q = tid & 3;
            gload16(Qh + (size_t)(m_blk + r) * HH + k0 + q * 8, &Ah[tid * 8]);
            gload16(Ql + (size_t)(m_blk + r) * HH + k0 + q * 8, &Al[tid * 8]);
        }
#pragma unroll
        for (int it = 0; it < 2; it++) {  // B-tile (128x32): two passes per array
            int c = it * 256 + tid;
            int r = c >> 2, q = c & 3;
            const char* brow = scr + (size_t)(n_blk + r) * OROWB + (size_t)(k0 + q * 8) * 2;
            gload16(brow + XDHI, &Bh[c * 8]);
            gload16(brow + XDLO, &Bl[c * 8]);
        }
        __syncthreads();
        bf16x8 ah[2], al[2], bh[4], bl[4];
#pragma unroll
        for (int i = 0; i < 2; i++) {
            int ra = (wm * 32 + i * 16 + r15) * 32 + quad * 8;
            ah[i] = *(const bf16x8*)&Ah[ra];
            al[i] = *(const bf16x8*)&Al[ra];
        }
#pragma unroll
        for (int j = 0; j < 4; j++) {
            int rb = (wn * 64 + j * 16 + r15) * 32 + quad * 8;
            bh[j] = *(const bf16x8*)&Bh[rb];
            bl[j] = *(const bf16x8*)&Bl[rb];
        }
#pragma unroll
        for (int i = 0; i < 2; i++)
#pragma unroll
            for (int j = 0; j < 4; j++) {
                acc[i][j] = __builtin_amdgcn_mfma_f32_16x16x32_bf16(ah[i], bh[j], acc[i][j], 0, 0, 0);
                acc[i][j] = __builtin_amdgcn_mfma_f32_16x16x32_bf16(ah[i], bl[j], acc[i][j], 0, 0, 0);
                acc[i][j] = __builtin_amdgcn_mfma_f32_16x16x32_bf16(al[i], bh[j], acc[i][j], 0, 0, 0);
            }
        __syncthreads();
    }
    float* Lb = L + (size_t)b * TT * TT;
#pragma unroll
    for (int j = 0; j < 4; j++) {
        int col = n_blk + wn * 64 + j * 16 + r15;  // s
#pragma unroll
        for (int i = 0; i < 2; i++) {
            int row0 = m_blk + wm * 32 + i * 16 + quad * 4;  // t
#pragma unroll
            for (int r = 0; r < 4; r++) Lb[(size_t)(row0 + r) * TT + col] = acc[i][j][r];
        }
    }
}

// ---- softmax over t (column) of L -> AQt[t][s] ----
__global__ void softmax_col_kernel(const float* __restrict__ L, __bf16* __restrict__ AQt) {
    int s = blockIdx.x, b = blockIdx.y;
    int tid = threadIdx.x;  // 128
    const float* Lb = L + (size_t)b * TT * TT;
    float v0 = Lb[(size_t)tid * TT + s];
    float v1 = Lb[(size_t)(tid + 128) * TT + s];
    float v2 = Lb[(size_t)(tid + 256) * TT + s];
    __shared__ float red[128];
    red[tid] = fmaxf(fmaxf(v0, v1), v2);
    __syncthreads();
    for (int off = 64; off > 0; off >>= 1) {
        if (tid < off) red[tid] = fmaxf(red[tid], red[tid + off]);
        __syncthreads();
    }
    float mx = red[0];
    __syncthreads();
    float e0 = __expf(v0 - mx), e1 = __expf(v1 - mx), e2 = __expf(v2 - mx);
    red[tid] = e0 + e1 + e2;
    __syncthreads();
    for (int off = 64; off > 0; off >>= 1) {
        if (tid < off) red[tid] += red[tid + off];
        __syncthreads();
    }
    float inv = 1.0f / red[0];
    __bf16* Ab = AQt + (size_t)b * TT * TT;
    Ab[(size_t)tid * TT + s] = (__bf16)(e0 * inv);
    Ab[(size_t)(tid + 128) * TT + s] = (__bf16)(e1 * inv);
    Ab[(size_t)(tid + 256) * TT + s] = (__bf16)(e2 * inv);
}

// ---- softmax over s (row) of L -> ADt[s][t] (transposed store) ----
__global__ void softmax_row_kernel(const float* __restrict__ L, __bf16* __restrict__ ADt) {
    int t = blockIdx.x, b = blockIdx.y;
    int tid = threadIdx.x;  // 128
    const float* Lb = L + (size_t)b * TT * TT + (size_t)t * TT;
    float v0 = Lb[tid], v1 = Lb[tid + 128], v2 = Lb[tid + 256];
    __shared__ float red[128];
    red[tid] = fmaxf(fmaxf(v0, v1), v2);
    __syncthreads();
    for (int off = 64; off > 0; off >>= 1) {
        if (tid < off) red[tid] = fmaxf(red[tid], red[tid + off]);
        __syncthreads();
    }
    float mx = red[0];
    __syncthreads();
    float e0 = __expf(v0 - mx), e1 = __expf(v1 - mx), e2 = __expf(v2 - mx);
    red[tid] = e0 + e1 + e2;
    __syncthreads();
    for (int off = 64; off > 0; off >>= 1) {
        if (tid < off) red[tid] += red[tid + off];
        __syncthreads();
    }
    float inv = 1.0f / red[0];
    __bf16* Ab = ADt + (size_t)b * TT * TT;
    Ab[(size_t)tid * TT + t] = (__bf16)(e0 * inv);
    Ab[(size_t)(tid + 128) * TT + t] = (__bf16)(e1 * inv);
    Ab[(size_t)(tid + 256) * TT + t] = (__bf16)(e2 * inv);
}

// ---- gemm3: C_Q[h][t] = sum_s Dt[h][s]*AQt[t][s] -> M4 rows 768..1535 ----
__global__ __launch_bounds__(256) void gemm3_kernel(
    const __bf16* __restrict__ Dt, const __bf16* __restrict__ AQt,
    __bf16* __restrict__ M4) {
    __shared__ __bf16 As[128 * 32], Bs[128 * 32];
    const int b = blockIdx.z;
    const int m_blk = blockIdx.y * 128, n_blk = blockIdx.x * 128;
    const int tid = threadIdx.x, lane = tid & 63, wave = tid >> 6;
    const int wm = wave >> 1, wn = wave & 1;
    const int r15 = lane & 15, quad = lane >> 4;
    const __bf16* Ab = Dt + (size_t)b * HH * TT;
    const __bf16* Bb = AQt + (size_t)b * TT * TT;
    f32x4 acc[4][4];
#pragma unroll
    for (int i = 0; i < 4; i++)
#pragma unroll
        for (int j = 0; j < 4; j++) acc[i][j] = (f32x4){0.f, 0.f, 0.f, 0.f};

    for (int k0 = 0; k0 < TT; k0 += 32) {
#pragma unroll
        for (int it = 0; it < 2; it++) {
            int c = it * 256 + tid;
            int r = c >> 2, q = c & 3;
            gload16(Ab + (size_t)(m_blk + r) * TT + k0 + q * 8, &As[c * 8]);
            gload16(Bb + (size_t)(n_blk + r) * TT + k0 + q * 8, &Bs[c * 8]);
        }
        __syncthreads();
        bf16x8 a[4], bf[4];
#pragma unroll
        for (int i = 0; i < 4; i++) {
            a[i] = *(const bf16x8*)&As[(wm * 64 + i * 16 + r15) * 32 + quad * 8];
            bf[i] = *(const bf16x8*)&Bs[(wn * 64 + i * 16 + r15) * 32 + quad * 8];
        }
#pragma unroll
        for (int i = 0; i < 4; i++)
#pragma unroll
            for (int j = 0; j < 4; j++)
                acc[i][j] = __builtin_amdgcn_mfma_f32_16x16x32_bf16(a[i], bf[j], acc[i][j], 0, 0, 0);
        __syncthreads();
    }
    __bf16* Mb = M4 + (size_t)b * 1536 * TT;
#pragma unroll
    for (int j = 0; j < 4; j++) {
        int col = n_blk + wn * 64 + j * 16 + r15;  // t
#pragma unroll
        for (int i = 0; i < 4; i++) {
            int row0 = m_blk + wm * 64 + i * 16 + quad * 4;  // h
#pragma unroll
            for (int r = 0; r < 4; r++)
                Mb[(size_t)(768 + row0 + r) * TT + col] = (__bf16)acc[i][j][r];
        }
    }
}

// ---- gemm4: out[s][i] = sum_t ADt[s][t]*M4[i][t], i<1536 ----
__global__ __launch_bounds__(256) void gemm4_kernel(
    const __bf16* __restrict__ ADt, const __bf16* __restrict__ M4,
    float* __restrict__ out) {
    __shared__ __bf16 As[128 * 32], Bs[128 * 32];
    const int b = blockIdx.z;
    const int m_blk = blockIdx.y * 128, n_blk = blockIdx.x * 128;
    const int tid = threadIdx.x, lane = tid & 63, wave = tid >> 6;
    const int wm = wave >> 1, wn = wave & 1;
    const int r15 = lane & 15, quad = lane >> 4;
    const __bf16* Ab = ADt + (size_t)b * TT * TT;
    const __bf16* Bb = M4 + (size_t)b * 1536 * TT;
    f32x4 acc[4][4];
#pragma unroll
    for (int i = 0; i < 4; i++)
#pragma unroll
        for (int j = 0; j < 4; j++) acc[i][j] = (f32x4){0.f, 0.f, 0.f, 0.f};

    for (int k0 = 0; k0 < TT; k0 += 32) {
#pragma unroll
        for (int it = 0; it < 2; it++) {
            int c = it * 256 + tid;
            int r = c >> 2, q = c & 3;
            gload16(Ab + (size_t)(m_blk + r) * TT + k0 + q * 8, &As[c * 8]);
            gload16(Bb + (size_t)(n_blk + r) * TT + k0 + q * 8, &Bs[c * 8]);
        }
        __syncthreads();
        bf16x8 a[4], bf[4];
#pragma unroll
        for (int i = 0; i < 4; i++) {
            a[i] = *(const bf16x8*)&As[(wm * 64 + i * 16 + r15) * 32 + quad * 8];
            bf[i] = *(const bf16x8*)&Bs[(wn * 64 + i * 16 + r15) * 32 + quad * 8];
        }
#pragma unroll
        for (int i = 0; i < 4; i++)
#pragma unroll
            for (int j = 0; j < 4; j++)
                acc[i][j] = __builtin_amdgcn_mfma_f32_16x16x32_bf16(a[i], bf[j], acc[i][j], 0, 0, 0);
        __syncthreads();
    }
    float* outb = out + (size_t)b * TT * 2304;
#pragma unroll
    for (int j = 0; j < 4; j++) {
        int col = n_blk + wn * 64 + j * 16 + r15;  // i
#pragma unroll
        for (int i = 0; i < 4; i++) {
            int row0 = m_blk + wm * 64 + i * 16 + quad * 4;  // s
#pragma unroll
            for (int r = 0; r < 4; r++)
                outb[(size_t)(row0 + r) * 2304 + col] = acc[i][j][r];
        }
    }
}

extern "C" void kernel_launch(void* const* d_in, const int* in_sizes, int n_in,
                              void* d_out, int out_size, void* d_ws, size_t ws_size,
                              hipStream_t stream) {
    const float* x = (const float*)d_in[0];
    const float* W = (const float*)d_in[1];
    const float* bias = (const float*)d_in[2];
    float* out = (float*)d_out;
    char* ws = (char*)d_ws;

    __bf16* Qhi = (__bf16*)(ws + 0);
    __bf16* Qlo = (__bf16*)(ws + 37748736);
    __bf16* M4 = (__bf16*)(ws + 75497472);
    __bf16* Dt = (__bf16*)(ws + 150994944);
    float* L = (float*)(ws + 188743680);
    // aliases (Qhi/Qlo dead after gemm2):
    __bf16* AQt = (__bf16*)(ws + 0);
    __bf16* ADt = (__bf16*)(ws + 37748736);
    // W split lives in the L region (L not written until gemm2; gemm1 reads W before)
    __bf16* Whi = (__bf16*)(ws + 188743680);
    __bf16* Wlo = Whi + 768 * 768;

    prep_kernel<<<dim3(24, 12, 64), dim3(32, 8), 0, stream>>>(x, Dt, out);
    splitX_kernel<<<9504, 256, 0, stream>>>(x, W, out, Whi, Wlo);
    gemm1_kernel<<<dim3(6, 3, 64), 256, 0, stream>>>(out, Whi, Wlo, bias, Qhi, Qlo, M4);
    gemm2_kernel<<<dim3(3, 6, 64), 256, 0, stream>>>(Qhi, Qlo, out, L);
    softmax_col_kernel<<<dim3(384, 64), 128, 0, stream>>>(L, AQt);
    softmax_row_kernel<<<dim3(384, 64), 128, 0, stream>>>(L, ADt);
    gemm3_kernel<<<dim3(3, 6, 64), 256, 0, stream>>>(Dt, AQt, M4);
    gemm4_kernel<<<dim3(12, 3, 64), 256, 0, stream>>>(ADt, M4, out);
}

// Round 3
// 885.110 us; speedup vs baseline: 1.1022x; 1.1022x over previous
//
#include <hip/hip_runtime.h>

// CoAttention: B=64, H=768, T=384. out (64,384,2304) fp32.
// ws layout (bytes), aliasing (Qhi/Qlo dead after gemm2 -> AQt/ADt):
//   Qhi bf16 (64,384,768)  @ 0           37,748,736   later: AQt bf16 (64,384,384) @ 0
//   Qlo bf16 (64,384,768)  @ 37748736    37,748,736   later: ADt bf16 (64,384,384) @ 37748736
//   M4  bf16 (64,1536,384) @ 75497472    75,497,472   rows 0..767 Qact^T, 768..1535 C_Q
//   Dt  bf16 (64,768,384)  @ 150994944   37,748,736
//   L   f32  (64,384,384)  @ 188743680   37,748,736   (first 2.36MB also used as Whi/Wlo
//                                                      scratch, dead once gemm2 writes L)

typedef __bf16 bf16x8 __attribute__((ext_vector_type(8)));
typedef __bf16 bf16x4 __attribute__((ext_vector_type(4)));
typedef float  f32x4  __attribute__((ext_vector_type(4)));

#define HH 768
#define TT 384

__device__ inline void split8(const float* __restrict__ p, bf16x8& hi, bf16x8& lo) {
    float4 f0 = *(const float4*)p;
    float4 f1 = *(const float4*)(p + 4);
    float f[8] = {f0.x, f0.y, f0.z, f0.w, f1.x, f1.y, f1.z, f1.w};
#pragma unroll
    for (int i = 0; i < 8; i++) {
        __bf16 h = (__bf16)f[i];
        hi[i] = h;
        lo[i] = (__bf16)(f[i] - (float)h);
    }
}

// async global->LDS, 16B per lane; LDS side must be wave-uniform base + lane*16
__device__ inline void gload16(const void* g, void* l) {
    __builtin_amdgcn_global_load_lds(
        (const __attribute__((address_space(1))) unsigned int*)g,
        (__attribute__((address_space(3))) unsigned int*)l, 16, 0, 0);
}

// ---- prep: Dt[b][h][s] = bf16(D[b][s][h]);  out[b][s][1536+h] = D[b][s][h] ----
__global__ void prep_kernel(const float* __restrict__ x, __bf16* __restrict__ Dt,
                            float* __restrict__ out) {
    __shared__ float tile[32][33];
    int b = blockIdx.z;
    int h0 = blockIdx.x * 32, s0 = blockIdx.y * 32;
    int tx = threadIdx.x, ty = threadIdx.y;
    const float* src = x + ((size_t)b * HH + TT) * HH;  // D rows
    float* outb = out + (size_t)b * TT * 2304;
#pragma unroll
    for (int j = 0; j < 4; j++) {
        int s = s0 + ty + 8 * j, h = h0 + tx;
        float v = src[(size_t)s * HH + h];
        tile[ty + 8 * j][tx] = v;
        outb[(size_t)s * 2304 + 1536 + h] = v;
    }
    __syncthreads();
    __bf16* Dtb = Dt + (size_t)b * HH * TT;
#pragma unroll
    for (int j = 0; j < 4; j++) {
        int h = h0 + ty + 8 * j, s = s0 + tx;
        Dtb[(size_t)h * TT + s] = (__bf16)tile[tx][ty + 8 * j];
    }
}

// ---- splitW: Whi/Wlo bf16 (768x768 each), stored in L region (dead until gemm2) ----
__global__ void splitW_kernel(const float* __restrict__ W, __bf16* __restrict__ Whi,
                              __bf16* __restrict__ Wlo) {
    int idx = blockIdx.x * 256 + threadIdx.x;  // 0..73727, covers 768*768/8
    bf16x8 h, l;
    split8(W + (size_t)idx * 8, h, l);
    *(bf16x8*)&Whi[(size_t)idx * 8] = h;
    *(bf16x8*)&Wlo[(size_t)idx * 8] = l;
}

// ---- gemm1: Qact = tanh(xQ @ W^T + b), split-precision (3 MFMA), 128x128 tile.
// A-side: in-loop split8 from x (no extra HBM pass; x Q-panel is L2-resident per batch).
// B-side: global_load_lds from pre-split Whi/Wlo (removes half the in-loop split VALU;
// R1/R2 showed pre-splitting the big activations is net-negative, W is free). ----
__global__ __launch_bounds__(256) void gemm1_kernel(
    const float* __restrict__ x, const __bf16* __restrict__ Whi,
    const __bf16* __restrict__ Wlo, const float* __restrict__ bias,
    __bf16* __restrict__ Qhi, __bf16* __restrict__ Qlo, __bf16* __restrict__ M4) {
    __shared__ __bf16 Ah[128 * 32], Al[128 * 32], Bh[128 * 32], Bl[128 * 32];
    const int b = blockIdx.z;
    const int m_blk = blockIdx.y * 128, n_blk = blockIdx.x * 128;
    const int tid = threadIdx.x, lane = tid & 63, wave = tid >> 6;
    const int wm = wave >> 1, wn = wave & 1;
    const int r15 = lane & 15, quad = lane >> 4;
    const float* Abase = x + (size_t)b * HH * HH;  // Q rows
    f32x4 acc[4][4];
#pragma unroll
    for (int i = 0; i < 4; i++)
#pragma unroll
        for (int j = 0; j < 4; j++) acc[i][j] = (f32x4){0.f, 0.f, 0.f, 0.f};

    for (int k0 = 0; k0 < HH; k0 += 32) {
#pragma unroll
        for (int it = 0; it < 2; it++) {
            int c = it * 256 + tid;
            int r = c >> 2, q = c & 3;
            gload16(Whi + (size_t)(n_blk + r) * HH + k0 + q * 8, &Bh[c * 8]);
            gload16(Wlo + (size_t)(n_blk + r) * HH + k0 + q * 8, &Bl[c * 8]);
            bf16x8 h, l;
            split8(Abase + (size_t)(m_blk + r) * HH + k0 + q * 8, h, l);
            *(bf16x8*)&Ah[c * 8] = h;
            *(bf16x8*)&Al[c * 8] = l;
        }
        __syncthreads();
        bf16x8 ah[4], al[4], bh[4], bl[4];
#pragma unroll
        for (int i = 0; i < 4; i++) {
            int ra = (wm * 64 + i * 16 + r15) * 32 + quad * 8;
            ah[i] = *(const bf16x8*)&Ah[ra];
            al[i] = *(const bf16x8*)&Al[ra];
            int rb = (wn * 64 + i * 16 + r15) * 32 + quad * 8;
            bh[i] = *(const bf16x8*)&Bh[rb];
            bl[i] = *(const bf16x8*)&Bl[rb];
        }
#pragma unroll
        for (int i = 0; i < 4; i++)
#pragma unroll
            for (int j = 0; j < 4; j++) {
                acc[i][j] = __builtin_amdgcn_mfma_f32_16x16x32_bf16(ah[i], bh[j], acc[i][j], 0, 0, 0);
                acc[i][j] = __builtin_amdgcn_mfma_f32_16x16x32_bf16(ah[i], bl[j], acc[i][j], 0, 0, 0);
                acc[i][j] = __builtin_amdgcn_mfma_f32_16x16x32_bf16(al[i], bh[j], acc[i][j], 0, 0, 0);
            }
        __syncthreads();
    }
    __bf16* Qh = Qhi + (size_t)b * TT * HH;
    __bf16* Ql = Qlo + (size_t)b * TT * HH;
    __bf16* Mb = M4 + (size_t)b * 1536 * TT;
#pragma unroll
    for (int j = 0; j < 4; j++) {
        int col = n_blk + wn * 64 + j * 16 + r15;  // o
        float bv = bias[col];
#pragma unroll
        for (int i = 0; i < 4; i++) {
            int row0 = m_blk + wm * 64 + i * 16 + quad * 4;  // t
            bf16x4 mrow;
#pragma unroll
            for (int r = 0; r < 4; r++) {
                float v = tanhf(acc[i][j][r] + bv);
                __bf16 qh = (__bf16)v;
                Qh[(size_t)(row0 + r) * HH + col] = qh;
                Ql[(size_t)(row0 + r) * HH + col] = (__bf16)(v - (float)qh);
                mrow[r] = qh;
            }
            *(bf16x4*)&Mb[(size_t)col * TT + row0] = mrow;
        }
    }
}

// ---- gemm2: L[t][s] = sum_h Qact[t][h]*D[s][h], split-precision (R0 form) ----
__global__ __launch_bounds__(256) void gemm2_kernel(
    const __bf16* __restrict__ Qhi, const __bf16* __restrict__ Qlo,
    const float* __restrict__ x, float* __restrict__ L) {
    __shared__ __bf16 Ah[128 * 32], Al[128 * 32], Bh[128 * 32], Bl[128 * 32];
    const int b = blockIdx.z;
    const int m_blk = blockIdx.y * 128, n_blk = blockIdx.x * 128;
    const int tid = threadIdx.x, lane = tid & 63, wave = tid >> 6;
    const int wm = wave >> 1, wn = wave & 1;
    const int r15 = lane & 15, quad = lane >> 4;
    const __bf16* Qh = Qhi + (size_t)b * TT * HH;
    const __bf16* Ql = Qlo + (size_t)b * TT * HH;
    const float* Dbase = x + ((size_t)b * HH + TT) * HH;  // D rows
    f32x4 acc[4][4];
#pragma unroll
    for (int i = 0; i < 4; i++)
#pragma unroll
        for (int j = 0; j < 4; j++) acc[i][j] = (f32x4){0.f, 0.f, 0.f, 0.f};

    for (int k0 = 0; k0 < HH; k0 += 32) {
#pragma unroll
        for (int it = 0; it < 2; it++) {
            int c = it * 256 + tid;
            int r = c >> 2, q = c & 3;
            gload16(Qh + (size_t)(m_blk + r) * HH + k0 + q * 8, &Ah[c * 8]);
            gload16(Ql + (size_t)(m_blk + r) * HH + k0 + q * 8, &Al[c * 8]);
            bf16x8 h, l;
            split8(Dbase + (size_t)(n_blk + r) * HH + k0 + q * 8, h, l);
            *(bf16x8*)&Bh[c * 8] = h;
            *(bf16x8*)&Bl[c * 8] = l;
        }
        __syncthreads();
        bf16x8 ah[4], al[4], bh[4], bl[4];
#pragma unroll
        for (int i = 0; i < 4; i++) {
            int ra = (wm * 64 + i * 16 + r15) * 32 + quad * 8;
            ah[i] = *(const bf16x8*)&Ah[ra];
            al[i] = *(const bf16x8*)&Al[ra];
            int rb = (wn * 64 + i * 16 + r15) * 32 + quad * 8;
            bh[i] = *(const bf16x8*)&Bh[rb];
            bl[i] = *(const bf16x8*)&Bl[rb];
        }
#pragma unroll
        for (int i = 0; i < 4; i++)
#pragma unroll
            for (int j = 0; j < 4; j++) {
                acc[i][j] = __builtin_amdgcn_mfma_f32_16x16x32_bf16(ah[i], bh[j], acc[i][j], 0, 0, 0);
                acc[i][j] = __builtin_amdgcn_mfma_f32_16x16x32_bf16(ah[i], bl[j], acc[i][j], 0, 0, 0);
                acc[i][j] = __builtin_amdgcn_mfma_f32_16x16x32_bf16(al[i], bh[j], acc[i][j], 0, 0, 0);
            }
        __syncthreads();
    }
    float* Lb = L + (size_t)b * TT * TT;
#pragma unroll
    for (int j = 0; j < 4; j++) {
        int col = n_blk + wn * 64 + j * 16 + r15;  // s
#pragma unroll
        for (int i = 0; i < 4; i++) {
            int row0 = m_blk + wm * 64 + i * 16 + quad * 4;  // t
#pragma unroll
            for (int r = 0; r < 4; r++) Lb[(size_t)(row0 + r) * TT + col] = acc[i][j][r];
        }
    }
}

// ---- softmax over t (column) of L -> AQt[t][s] ----
__global__ void softmax_col_kernel(const float* __restrict__ L, __bf16* __restrict__ AQt) {
    int s = blockIdx.x, b = blockIdx.y;
    int tid = threadIdx.x;  // 128
    const float* Lb = L + (size_t)b * TT * TT;
    float v0 = Lb[(size_t)tid * TT + s];
    float v1 = Lb[(size_t)(tid + 128) * TT + s];
    float v2 = Lb[(size_t)(tid + 256) * TT + s];
    __shared__ float red[128];
    red[tid] = fmaxf(fmaxf(v0, v1), v2);
    __syncthreads();
    for (int off = 64; off > 0; off >>= 1) {
        if (tid < off) red[tid] = fmaxf(red[tid], red[tid + off]);
        __syncthreads();
    }
    float mx = red[0];
    __syncthreads();
    float e0 = __expf(v0 - mx), e1 = __expf(v1 - mx), e2 = __expf(v2 - mx);
    red[tid] = e0 + e1 + e2;
    __syncthreads();
    for (int off = 64; off > 0; off >>= 1) {
        if (tid < off) red[tid] += red[tid + off];
        __syncthreads();
    }
    float inv = 1.0f / red[0];
    __bf16* Ab = AQt + (size_t)b * TT * TT;
    Ab[(size_t)tid * TT + s] = (__bf16)(e0 * inv);
    Ab[(size_t)(tid + 128) * TT + s] = (__bf16)(e1 * inv);
    Ab[(size_t)(tid + 256) * TT + s] = (__bf16)(e2 * inv);
}

// ---- softmax over s (row) of L -> ADt[s][t] (transposed store) ----
__global__ void softmax_row_kernel(const float* __restrict__ L, __bf16* __restrict__ ADt) {
    int t = blockIdx.x, b = blockIdx.y;
    int tid = threadIdx.x;  // 128
    const float* Lb = L + (size_t)b * TT * TT + (size_t)t * TT;
    float v0 = Lb[tid], v1 = Lb[tid + 128], v2 = Lb[tid + 256];
    __shared__ float red[128];
    red[tid] = fmaxf(fmaxf(v0, v1), v2);
    __syncthreads();
    for (int off = 64; off > 0; off >>= 1) {
        if (tid < off) red[tid] = fmaxf(red[tid], red[tid + off]);
        __syncthreads();
    }
    float mx = red[0];
    __syncthreads();
    float e0 = __expf(v0 - mx), e1 = __expf(v1 - mx), e2 = __expf(v2 - mx);
    red[tid] = e0 + e1 + e2;
    __syncthreads();
    for (int off = 64; off > 0; off >>= 1) {
        if (tid < off) red[tid] += red[tid + off];
        __syncthreads();
    }
    float inv = 1.0f / red[0];
    __bf16* Ab = ADt + (size_t)b * TT * TT;
    Ab[(size_t)tid * TT + t] = (__bf16)(e0 * inv);
    Ab[(size_t)(tid + 128) * TT + t] = (__bf16)(e1 * inv);
    Ab[(size_t)(tid + 256) * TT + t] = (__bf16)(e2 * inv);
}

// ---- gemm3: C_Q[h][t] = sum_s Dt[h][s]*AQt[t][s] -> M4 rows 768..1535 ----
__global__ __launch_bounds__(256) void gemm3_kernel(
    const __bf16* __restrict__ Dt, const __bf16* __restrict__ AQt,
    __bf16* __restrict__ M4) {
    __shared__ __bf16 As[128 * 32], Bs[128 * 32];
    const int b = blockIdx.z;
    const int m_blk = blockIdx.y * 128, n_blk = blockIdx.x * 128;
    const int tid = threadIdx.x, lane = tid & 63, wave = tid >> 6;
    const int wm = wave >> 1, wn = wave & 1;
    const int r15 = lane & 15, quad = lane >> 4;
    const __bf16* Ab = Dt + (size_t)b * HH * TT;
    const __bf16* Bb = AQt + (size_t)b * TT * TT;
    f32x4 acc[4][4];
#pragma unroll
    for (int i = 0; i < 4; i++)
#pragma unroll
        for (int j = 0; j < 4; j++) acc[i][j] = (f32x4){0.f, 0.f, 0.f, 0.f};

    for (int k0 = 0; k0 < TT; k0 += 32) {
#pragma unroll
        for (int it = 0; it < 2; it++) {
            int c = it * 256 + tid;
            int r = c >> 2, q = c & 3;
            gload16(Ab + (size_t)(m_blk + r) * TT + k0 + q * 8, &As[c * 8]);
            gload16(Bb + (size_t)(n_blk + r) * TT + k0 + q * 8, &Bs[c * 8]);
        }
        __syncthreads();
        bf16x8 a[4], bf[4];
#pragma unroll
        for (int i = 0; i < 4; i++) {
            a[i] = *(const bf16x8*)&As[(wm * 64 + i * 16 + r15) * 32 + quad * 8];
            bf[i] = *(const bf16x8*)&Bs[(wn * 64 + i * 16 + r15) * 32 + quad * 8];
        }
#pragma unroll
        for (int i = 0; i < 4; i++)
#pragma unroll
            for (int j = 0; j < 4; j++)
                acc[i][j] = __builtin_amdgcn_mfma_f32_16x16x32_bf16(a[i], bf[j], acc[i][j], 0, 0, 0);
        __syncthreads();
    }
    __bf16* Mb = M4 + (size_t)b * 1536 * TT;
#pragma unroll
    for (int j = 0; j < 4; j++) {
        int col = n_blk + wn * 64 + j * 16 + r15;  // t
#pragma unroll
        for (int i = 0; i < 4; i++) {
            int row0 = m_blk + wm * 64 + i * 16 + quad * 4;  // h
#pragma unroll
            for (int r = 0; r < 4; r++)
                Mb[(size_t)(768 + row0 + r) * TT + col] = (__bf16)acc[i][j][r];
        }
    }
}

// ---- gemm4: out[s][i] = sum_t ADt[s][t]*M4[i][t], i<1536 ----
__global__ __launch_bounds__(256) void gemm4_kernel(
    const __bf16* __restrict__ ADt, const __bf16* __restrict__ M4,
    float* __restrict__ out) {
    __shared__ __bf16 As[128 * 32], Bs[128 * 32];
    const int b = blockIdx.z;
    const int m_blk = blockIdx.y * 128, n_blk = blockIdx.x * 128;
    const int tid = threadIdx.x, lane = tid & 63, wave = tid >> 6;
    const int wm = wave >> 1, wn = wave & 1;
    const int r15 = lane & 15, quad = lane >> 4;
    const __bf16* Ab = ADt + (size_t)b * TT * TT;
    const __bf16* Bb = M4 + (size_t)b * 1536 * TT;
    f32x4 acc[4][4];
#pragma unroll
    for (int i = 0; i < 4; i++)
#pragma unroll
        for (int j = 0; j < 4; j++) acc[i][j] = (f32x4){0.f, 0.f, 0.f, 0.f};

    for (int k0 = 0; k0 < TT; k0 += 32) {
#pragma unroll
        for (int it = 0; it < 2; it++) {
            int c = it * 256 + tid;
            int r = c >> 2, q = c & 3;
            gload16(Ab + (size_t)(m_blk + r) * TT + k0 + q * 8, &As[c * 8]);
            gload16(Bb + (size_t)(n_blk + r) * TT + k0 + q * 8, &Bs[c * 8]);
        }
        __syncthreads();
        bf16x8 a[4], bf[4];
#pragma unroll
        for (int i = 0; i < 4; i++) {
            a[i] = *(const bf16x8*)&As[(wm * 64 + i * 16 + r15) * 32 + quad * 8];
            bf[i] = *(const bf16x8*)&Bs[(wn * 64 + i * 16 + r15) * 32 + quad * 8];
        }
#pragma unroll
        for (int i = 0; i < 4; i++)
#pragma unroll
            for (int j = 0; j < 4; j++)
                acc[i][j] = __builtin_amdgcn_mfma_f32_16x16x32_bf16(a[i], bf[j], acc[i][j], 0, 0, 0);
        __syncthreads();
    }
    float* outb = out + (size_t)b * TT * 2304;
#pragma unroll
    for (int j = 0; j < 4; j++) {
        int col = n_blk + wn * 64 + j * 16 + r15;  // i
#pragma unroll
        for (int i = 0; i < 4; i++) {
            int row0 = m_blk + wm * 64 + i * 16 + quad * 4;  // s
#pragma unroll
            for (int r = 0; r < 4; r++)
                outb[(size_t)(row0 + r) * 2304 + col] = acc[i][j][r];
        }
    }
}

extern "C" void kernel_launch(void* const* d_in, const int* in_sizes, int n_in,
                              void* d_out, int out_size, void* d_ws, size_t ws_size,
                              hipStream_t stream) {
    const float* x = (const float*)d_in[0];
    const float* W = (const float*)d_in[1];
    const float* bias = (const float*)d_in[2];
    float* out = (float*)d_out;
    char* ws = (char*)d_ws;

    __bf16* Qhi = (__bf16*)(ws + 0);
    __bf16* Qlo = (__bf16*)(ws + 37748736);
    __bf16* M4 = (__bf16*)(ws + 75497472);
    __bf16* Dt = (__bf16*)(ws + 150994944);
    float* L = (float*)(ws + 188743680);
    // aliases (Qhi/Qlo dead after gemm2):
    __bf16* AQt = (__bf16*)(ws + 0);
    __bf16* ADt = (__bf16*)(ws + 37748736);
    // W split lives in the L region (L not written until gemm2; gemm1 reads W before)
    __bf16* Whi = (__bf16*)(ws + 188743680);
    __bf16* Wlo = Whi + 768 * 768;

    prep_kernel<<<dim3(24, 12, 64), dim3(32, 8), 0, stream>>>(x, Dt, out);
    splitW_kernel<<<288, 256, 0, stream>>>(W, Whi, Wlo);
    gemm1_kernel<<<dim3(6, 3, 64), 256, 0, stream>>>(x, Whi, Wlo, bias, Qhi, Qlo, M4);
    gemm2_kernel<<<dim3(3, 3, 64), 256, 0, stream>>>(Qhi, Qlo, x, L);
    softmax_col_kernel<<<dim3(384, 64), 128, 0, stream>>>(L, AQt);
    softmax_row_kernel<<<dim3(384, 64), 128, 0, stream>>>(L, ADt);
    gemm3_kernel<<<dim3(3, 6, 64), 256, 0, stream>>>(Dt, AQt, M4);
    gemm4_kernel<<<dim3(12, 3, 64), 256, 0, stream>>>(ADt, M4, out);
}

// Round 4
// 815.828 us; speedup vs baseline: 1.1958x; 1.0849x over previous
//
#include <hip/hip_runtime.h>

// CoAttention: B=64, H=768, T=384. out (64,384,2304) fp32.
// ws layout (bytes), aliasing (Qhi/Qlo dead after gemm2 -> AQt/ADt):
//   Qhi bf16 (64,384,768)  @ 0           37,748,736   later: AQt bf16 (64,384,384) @ 0
//   Qlo bf16 (64,384,768)  @ 37748736    37,748,736   later: ADt bf16 (64,384,384) @ 37748736
//   M4  bf16 (64,1536,384) @ 75497472    75,497,472   rows 0..767 Qact^T, 768..1535 C_Q
//   Dt  bf16 (64,768,384)  @ 150994944   37,748,736
//   L   f32  (64,384,384)  @ 188743680   37,748,736   (first 2.36MB also used as Whi/Wlo
//                                                      scratch, dead once gemm2 writes L)
// Staging discipline (R3 lesson): within one k-loop use ONE staging mechanism.
// gemm1/gemm2: all register->ds_write. gemm3/gemm4: all global_load_lds.

typedef __bf16 bf16x8 __attribute__((ext_vector_type(8)));
typedef __bf16 bf16x4 __attribute__((ext_vector_type(4)));
typedef float  f32x4  __attribute__((ext_vector_type(4)));

#define HH 768
#define TT 384

__device__ inline void split8(const float* __restrict__ p, bf16x8& hi, bf16x8& lo) {
    float4 f0 = *(const float4*)p;
    float4 f1 = *(const float4*)(p + 4);
    float f[8] = {f0.x, f0.y, f0.z, f0.w, f1.x, f1.y, f1.z, f1.w};
#pragma unroll
    for (int i = 0; i < 8; i++) {
        __bf16 h = (__bf16)f[i];
        hi[i] = h;
        lo[i] = (__bf16)(f[i] - (float)h);
    }
}

// async global->LDS, 16B per lane; LDS side must be wave-uniform base + lane*16
__device__ inline void gload16(const void* g, void* l) {
    __builtin_amdgcn_global_load_lds(
        (const __attribute__((address_space(1))) unsigned int*)g,
        (__attribute__((address_space(3))) unsigned int*)l, 16, 0, 0);
}

// ---- prep: Dt[b][h][s] = bf16(D[b][s][h]);  out[b][s][1536+h] = D[b][s][h] ----
__global__ void prep_kernel(const float* __restrict__ x, __bf16* __restrict__ Dt,
                            float* __restrict__ out) {
    __shared__ float tile[32][33];
    int b = blockIdx.z;
    int h0 = blockIdx.x * 32, s0 = blockIdx.y * 32;
    int tx = threadIdx.x, ty = threadIdx.y;
    const float* src = x + ((size_t)b * HH + TT) * HH;  // D rows
    float* outb = out + (size_t)b * TT * 2304;
#pragma unroll
    for (int j = 0; j < 4; j++) {
        int s = s0 + ty + 8 * j, h = h0 + tx;
        float v = src[(size_t)s * HH + h];
        tile[ty + 8 * j][tx] = v;
        outb[(size_t)s * 2304 + 1536 + h] = v;
    }
    __syncthreads();
    __bf16* Dtb = Dt + (size_t)b * HH * TT;
#pragma unroll
    for (int j = 0; j < 4; j++) {
        int h = h0 + ty + 8 * j, s = s0 + tx;
        Dtb[(size_t)h * TT + s] = (__bf16)tile[tx][ty + 8 * j];
    }
}

// ---- splitW: Whi/Wlo bf16 (768x768 each), stored in L region (dead until gemm2) ----
__global__ void splitW_kernel(const float* __restrict__ W, __bf16* __restrict__ Whi,
                              __bf16* __restrict__ Wlo) {
    int idx = blockIdx.x * 256 + threadIdx.x;  // 0..73727, covers 768*768/8
    bf16x8 h, l;
    split8(W + (size_t)idx * 8, h, l);
    *(bf16x8*)&Whi[(size_t)idx * 8] = h;
    *(bf16x8*)&Wlo[(size_t)idx * 8] = l;
}

// ---- gemm1: Qact = tanh(xQ @ W^T + b), split-precision (3 MFMA), 128x128 tile.
// Uniform staging: A = split8(x) -> ds_write; B = bf16x8 loads of Whi/Wlo -> ds_write. ----
__global__ __launch_bounds__(256) void gemm1_kernel(
    const float* __restrict__ x, const __bf16* __restrict__ Whi,
    const __bf16* __restrict__ Wlo, const float* __restrict__ bias,
    __bf16* __restrict__ Qhi, __bf16* __restrict__ Qlo, __bf16* __restrict__ M4) {
    __shared__ __bf16 Ah[128 * 32], Al[128 * 32], Bh[128 * 32], Bl[128 * 32];
    const int b = blockIdx.z;
    const int m_blk = blockIdx.y * 128, n_blk = blockIdx.x * 128;
    const int tid = threadIdx.x, lane = tid & 63, wave = tid >> 6;
    const int wm = wave >> 1, wn = wave & 1;
    const int r15 = lane & 15, quad = lane >> 4;
    const float* Abase = x + (size_t)b * HH * HH;  // Q rows
    f32x4 acc[4][4];
#pragma unroll
    for (int i = 0; i < 4; i++)
#pragma unroll
        for (int j = 0; j < 4; j++) acc[i][j] = (f32x4){0.f, 0.f, 0.f, 0.f};

    for (int k0 = 0; k0 < HH; k0 += 32) {
#pragma unroll
        for (int it = 0; it < 2; it++) {
            int c = it * 256 + tid;
            int r = c >> 2, q = c & 3;
            bf16x8 wh = *(const bf16x8*)&Whi[(size_t)(n_blk + r) * HH + k0 + q * 8];
            bf16x8 wl = *(const bf16x8*)&Wlo[(size_t)(n_blk + r) * HH + k0 + q * 8];
            *(bf16x8*)&Bh[c * 8] = wh;
            *(bf16x8*)&Bl[c * 8] = wl;
            bf16x8 h, l;
            split8(Abase + (size_t)(m_blk + r) * HH + k0 + q * 8, h, l);
            *(bf16x8*)&Ah[c * 8] = h;
            *(bf16x8*)&Al[c * 8] = l;
        }
        __syncthreads();
        bf16x8 ah[4], al[4], bh[4], bl[4];
#pragma unroll
        for (int i = 0; i < 4; i++) {
            int ra = (wm * 64 + i * 16 + r15) * 32 + quad * 8;
            ah[i] = *(const bf16x8*)&Ah[ra];
            al[i] = *(const bf16x8*)&Al[ra];
            int rb = (wn * 64 + i * 16 + r15) * 32 + quad * 8;
            bh[i] = *(const bf16x8*)&Bh[rb];
            bl[i] = *(const bf16x8*)&Bl[rb];
        }
#pragma unroll
        for (int i = 0; i < 4; i++)
#pragma unroll
            for (int j = 0; j < 4; j++) {
                acc[i][j] = __builtin_amdgcn_mfma_f32_16x16x32_bf16(ah[i], bh[j], acc[i][j], 0, 0, 0);
                acc[i][j] = __builtin_amdgcn_mfma_f32_16x16x32_bf16(ah[i], bl[j], acc[i][j], 0, 0, 0);
                acc[i][j] = __builtin_amdgcn_mfma_f32_16x16x32_bf16(al[i], bh[j], acc[i][j], 0, 0, 0);
            }
        __syncthreads();
    }
    __bf16* Qh = Qhi + (size_t)b * TT * HH;
    __bf16* Ql = Qlo + (size_t)b * TT * HH;
    __bf16* Mb = M4 + (size_t)b * 1536 * TT;
#pragma unroll
    for (int j = 0; j < 4; j++) {
        int col = n_blk + wn * 64 + j * 16 + r15;  // o
        float bv = bias[col];
#pragma unroll
        for (int i = 0; i < 4; i++) {
            int row0 = m_blk + wm * 64 + i * 16 + quad * 4;  // t
            bf16x4 mrow;
#pragma unroll
            for (int r = 0; r < 4; r++) {
                float v = tanhf(acc[i][j][r] + bv);
                __bf16 qh = (__bf16)v;
                Qh[(size_t)(row0 + r) * HH + col] = qh;
                Ql[(size_t)(row0 + r) * HH + col] = (__bf16)(v - (float)qh);
                mrow[r] = qh;
            }
            *(bf16x4*)&Mb[(size_t)col * TT + row0] = mrow;
        }
    }
}

// ---- gemm2: L[t][s] = sum_h Qact[t][h]*D[s][h], split-precision.
// Uniform staging: A = bf16x8 loads of Qhi/Qlo -> ds_write; B = split8(x) -> ds_write. ----
__global__ __launch_bounds__(256) void gemm2_kernel(
    const __bf16* __restrict__ Qhi, const __bf16* __restrict__ Qlo,
    const float* __restrict__ x, float* __restrict__ L) {
    __shared__ __bf16 Ah[128 * 32], Al[128 * 32], Bh[128 * 32], Bl[128 * 32];
    const int b = blockIdx.z;
    const int m_blk = blockIdx.y * 128, n_blk = blockIdx.x * 128;
    const int tid = threadIdx.x, lane = tid & 63, wave = tid >> 6;
    const int wm = wave >> 1, wn = wave & 1;
    const int r15 = lane & 15, quad = lane >> 4;
    const __bf16* Qh = Qhi + (size_t)b * TT * HH;
    const __bf16* Ql = Qlo + (size_t)b * TT * HH;
    const float* Dbase = x + ((size_t)b * HH + TT) * HH;  // D rows
    f32x4 acc[4][4];
#pragma unroll
    for (int i = 0; i < 4; i++)
#pragma unroll
        for (int j = 0; j < 4; j++) acc[i][j] = (f32x4){0.f, 0.f, 0.f, 0.f};

    for (int k0 = 0; k0 < HH; k0 += 32) {
#pragma unroll
        for (int it = 0; it < 2; it++) {
            int c = it * 256 + tid;
            int r = c >> 2, q = c & 3;
            bf16x8 qh8 = *(const bf16x8*)&Qh[(size_t)(m_blk + r) * HH + k0 + q * 8];
            bf16x8 ql8 = *(const bf16x8*)&Ql[(size_t)(m_blk + r) * HH + k0 + q * 8];
            *(bf16x8*)&Ah[c * 8] = qh8;
            *(bf16x8*)&Al[c * 8] = ql8;
            bf16x8 h, l;
            split8(Dbase + (size_t)(n_blk + r) * HH + k0 + q * 8, h, l);
            *(bf16x8*)&Bh[c * 8] = h;
            *(bf16x8*)&Bl[c * 8] = l;
        }
        __syncthreads();
        bf16x8 ah[4], al[4], bh[4], bl[4];
#pragma unroll
        for (int i = 0; i < 4; i++) {
            int ra = (wm * 64 + i * 16 + r15) * 32 + quad * 8;
            ah[i] = *(const bf16x8*)&Ah[ra];
            al[i] = *(const bf16x8*)&Al[ra];
            int rb = (wn * 64 + i * 16 + r15) * 32 + quad * 8;
            bh[i] = *(const bf16x8*)&Bh[rb];
            bl[i] = *(const bf16x8*)&Bl[rb];
        }
#pragma unroll
        for (int i = 0; i < 4; i++)
#pragma unroll
            for (int j = 0; j < 4; j++) {
                acc[i][j] = __builtin_amdgcn_mfma_f32_16x16x32_bf16(ah[i], bh[j], acc[i][j], 0, 0, 0);
                acc[i][j] = __builtin_amdgcn_mfma_f32_16x16x32_bf16(ah[i], bl[j], acc[i][j], 0, 0, 0);
                acc[i][j] = __builtin_amdgcn_mfma_f32_16x16x32_bf16(al[i], bh[j], acc[i][j], 0, 0, 0);
            }
        __syncthreads();
    }
    float* Lb = L + (size_t)b * TT * TT;
#pragma unroll
    for (int j = 0; j < 4; j++) {
        int col = n_blk + wn * 64 + j * 16 + r15;  // s
#pragma unroll
        for (int i = 0; i < 4; i++) {
            int row0 = m_blk + wm * 64 + i * 16 + quad * 4;  // t
#pragma unroll
            for (int r = 0; r < 4; r++) Lb[(size_t)(row0 + r) * TT + col] = acc[i][j][r];
        }
    }
}

// ---- softmax over t (column) of L -> AQt[t][s], tiled & coalesced ----
// grid (6,64), block (64,4): block owns 64 columns of one batch; 3 coalesced row sweeps.
__global__ void softmax_col_kernel(const float* __restrict__ L, __bf16* __restrict__ AQt) {
    int b = blockIdx.y;
    int tx = threadIdx.x, ty = threadIdx.y;
    int s = blockIdx.x * 64 + tx;
    const float* Lb = L + (size_t)b * TT * TT;
    __shared__ float red[4][64];
    float mx = -1e30f;
    for (int t = ty; t < TT; t += 4) mx = fmaxf(mx, Lb[(size_t)t * TT + s]);
    red[ty][tx] = mx;
    __syncthreads();
    mx = fmaxf(fmaxf(red[0][tx], red[1][tx]), fmaxf(red[2][tx], red[3][tx]));
    float sum = 0.f;
    for (int t = ty; t < TT; t += 4) sum += __expf(Lb[(size_t)t * TT + s] - mx);
    __syncthreads();
    red[ty][tx] = sum;
    __syncthreads();
    float inv = 1.0f / (red[0][tx] + red[1][tx] + red[2][tx] + red[3][tx]);
    __bf16* Ab = AQt + (size_t)b * TT * TT;
    for (int t = ty; t < TT; t += 4)
        Ab[(size_t)t * TT + s] = (__bf16)(__expf(Lb[(size_t)t * TT + s] - mx) * inv);
}

// ---- softmax over s (row) of L -> ADt[s][t] (transposed store), tiled & coalesced ----
// grid (6,64), block (64,4): block owns 64 rows t; wave-shuffle row reduce;
// LDS bf16 tile then 128B-contiguous transposed stores.
__global__ void softmax_row_kernel(const float* __restrict__ L, __bf16* __restrict__ ADt) {
    int b = blockIdx.y;
    int t0 = blockIdx.x * 64;
    int tx = threadIdx.x, ty = threadIdx.y;
    int tid = ty * 64 + tx;
    const float* Lb = L + (size_t)b * TT * TT;
    __shared__ __bf16 ex[64][TT];  // 48 KB
    for (int rr = ty; rr < 64; rr += 4) {
        const float* row = Lb + (size_t)(t0 + rr) * TT;
        float v[6];
        float mx = -1e30f;
#pragma unroll
        for (int k = 0; k < 6; k++) {
            v[k] = row[tx + 64 * k];
            mx = fmaxf(mx, v[k]);
        }
#pragma unroll
        for (int off = 32; off > 0; off >>= 1) mx = fmaxf(mx, __shfl_xor(mx, off));
        float sum = 0.f;
#pragma unroll
        for (int k = 0; k < 6; k++) {
            v[k] = __expf(v[k] - mx);
            sum += v[k];
        }
#pragma unroll
        for (int off = 32; off > 0; off >>= 1) sum += __shfl_xor(sum, off);
        float inv = 1.0f / sum;
#pragma unroll
        for (int k = 0; k < 6; k++) ex[rr][tx + 64 * k] = (__bf16)(v[k] * inv);
    }
    __syncthreads();
    __bf16* Ab = ADt + (size_t)b * TT * TT;
    for (int s = tid; s < TT; s += 256) {
#pragma unroll
        for (int j = 0; j < 8; j++) {
            bf16x8 t8;
#pragma unroll
            for (int e = 0; e < 8; e++) t8[e] = ex[j * 8 + e][s];
            *(bf16x8*)&Ab[(size_t)s * TT + t0 + j * 8] = t8;
        }
    }
}

// ---- gemm3: C_Q[h][t] = sum_s Dt[h][s]*AQt[t][s] -> M4 rows 768..1535 ----
__global__ __launch_bounds__(256) void gemm3_kernel(
    const __bf16* __restrict__ Dt, const __bf16* __restrict__ AQt,
    __bf16* __restrict__ M4) {
    __shared__ __bf16 As[128 * 32], Bs[128 * 32];
    const int b = blockIdx.z;
    const int m_blk = blockIdx.y * 128, n_blk = blockIdx.x * 128;
    const int tid = threadIdx.x, lane = tid & 63, wave = tid >> 6;
    const int wm = wave >> 1, wn = wave & 1;
    const int r15 = lane & 15, quad = lane >> 4;
    const __bf16* Ab = Dt + (size_t)b * HH * TT;
    const __bf16* Bb = AQt + (size_t)b * TT * TT;
    f32x4 acc[4][4];
#pragma unroll
    for (int i = 0; i < 4; i++)
#pragma unroll
        for (int j = 0; j < 4; j++) acc[i][j] = (f32x4){0.f, 0.f, 0.f, 0.f};

    for (int k0 = 0; k0 < TT; k0 += 32) {
#pragma unroll
        for (int it = 0; it < 2; it++) {
            int c = it * 256 + tid;
            int r = c >> 2, q = c & 3;
            gload16(Ab + (size_t)(m_blk + r) * TT + k0 + q * 8, &As[c * 8]);
            gload16(Bb + (size_t)(n_blk + r) * TT + k0 + q * 8, &Bs[c * 8]);
        }
        __syncthreads();
        bf16x8 a[4], bf[4];
#pragma unroll
        for (int i = 0; i < 4; i++) {
            a[i] = *(const bf16x8*)&As[(wm * 64 + i * 16 + r15) * 32 + quad * 8];
            bf[i] = *(const bf16x8*)&Bs[(wn * 64 + i * 16 + r15) * 32 + quad * 8];
        }
#pragma unroll
        for (int i = 0; i < 4; i++)
#pragma unroll
            for (int j = 0; j < 4; j++)
                acc[i][j] = __builtin_amdgcn_mfma_f32_16x16x32_bf16(a[i], bf[j], acc[i][j], 0, 0, 0);
        __syncthreads();
    }
    __bf16* Mb = M4 + (size_t)b * 1536 * TT;
#pragma unroll
    for (int j = 0; j < 4; j++) {
        int col = n_blk + wn * 64 + j * 16 + r15;  // t
#pragma unroll
        for (int i = 0; i < 4; i++) {
            int row0 = m_blk + wm * 64 + i * 16 + quad * 4;  // h
#pragma unroll
            for (int r = 0; r < 4; r++)
                Mb[(size_t)(768 + row0 + r) * TT + col] = (__bf16)acc[i][j][r];
        }
    }
}

// ---- gemm4: out[s][i] = sum_t ADt[s][t]*M4[i][t], i<1536 ----
__global__ __launch_bounds__(256) void gemm4_kernel(
    const __bf16* __restrict__ ADt, const __bf16* __restrict__ M4,
    float* __restrict__ out) {
    __shared__ __bf16 As[128 * 32], Bs[128 * 32];
    const int b = blockIdx.z;
    const int m_blk = blockIdx.y * 128, n_blk = blockIdx.x * 128;
    const int tid = threadIdx.x, lane = tid & 63, wave = tid >> 6;
    const int wm = wave >> 1, wn = wave & 1;
    const int r15 = lane & 15, quad = lane >> 4;
    const __bf16* Ab = ADt + (size_t)b * TT * TT;
    const __bf16* Bb = M4 + (size_t)b * 1536 * TT;
    f32x4 acc[4][4];
#pragma unroll
    for (int i = 0; i < 4; i++)
#pragma unroll
        for (int j = 0; j < 4; j++) acc[i][j] = (f32x4){0.f, 0.f, 0.f, 0.f};

    for (int k0 = 0; k0 < TT; k0 += 32) {
#pragma unroll
        for (int it = 0; it < 2; it++) {
            int c = it * 256 + tid;
            int r = c >> 2, q = c & 3;
            gload16(Ab + (size_t)(m_blk + r) * TT + k0 + q * 8, &As[c * 8]);
            gload16(Bb + (size_t)(n_blk + r) * TT + k0 + q * 8, &Bs[c * 8]);
        }
        __syncthreads();
        bf16x8 a[4], bf[4];
#pragma unroll
        for (int i = 0; i < 4; i++) {
            a[i] = *(const bf16x8*)&As[(wm * 64 + i * 16 + r15) * 32 + quad * 8];
            bf[i] = *(const bf16x8*)&Bs[(wn * 64 + i * 16 + r15) * 32 + quad * 8];
        }
#pragma unroll
        for (int i = 0; i < 4; i++)
#pragma unroll
            for (int j = 0; j < 4; j++)
                acc[i][j] = __builtin_amdgcn_mfma_f32_16x16x32_bf16(a[i], bf[j], acc[i][j], 0, 0, 0);
        __syncthreads();
    }
    float* outb = out + (size_t)b * TT * 2304;
#pragma unroll
    for (int j = 0; j < 4; j++) {
        int col = n_blk + wn * 64 + j * 16 + r15;  // i
#pragma unroll
        for (int i = 0; i < 4; i++) {
            int row0 = m_blk + wm * 64 + i * 16 + quad * 4;  // s
#pragma unroll
            for (int r = 0; r < 4; r++)
                outb[(size_t)(row0 + r) * 2304 + col] = acc[i][j][r];
        }
    }
}

extern "C" void kernel_launch(void* const* d_in, const int* in_sizes, int n_in,
                              void* d_out, int out_size, void* d_ws, size_t ws_size,
                              hipStream_t stream) {
    const float* x = (const float*)d_in[0];
    const float* W = (const float*)d_in[1];
    const float* bias = (const float*)d_in[2];
    float* out = (float*)d_out;
    char* ws = (char*)d_ws;

    __bf16* Qhi = (__bf16*)(ws + 0);
    __bf16* Qlo = (__bf16*)(ws + 37748736);
    __bf16* M4 = (__bf16*)(ws + 75497472);
    __bf16* Dt = (__bf16*)(ws + 150994944);
    float* L = (float*)(ws + 188743680);
    // aliases (Qhi/Qlo dead after gemm2):
    __bf16* AQt = (__bf16*)(ws + 0);
    __bf16* ADt = (__bf16*)(ws + 37748736);
    // W split lives in the L region (L not written until gemm2; gemm1 reads W before)
    __bf16* Whi = (__bf16*)(ws + 188743680);
    __bf16* Wlo = Whi + 768 * 768;

    prep_kernel<<<dim3(24, 12, 64), dim3(32, 8), 0, stream>>>(x, Dt, out);
    splitW_kernel<<<288, 256, 0, stream>>>(W, Whi, Wlo);
    gemm1_kernel<<<dim3(6, 3, 64), 256, 0, stream>>>(x, Whi, Wlo, bias, Qhi, Qlo, M4);
    gemm2_kernel<<<dim3(3, 3, 64), 256, 0, stream>>>(Qhi, Qlo, x, L);
    softmax_col_kernel<<<dim3(6, 64), dim3(64, 4), 0, stream>>>(L, AQt);
    softmax_row_kernel<<<dim3(6, 64), dim3(64, 4), 0, stream>>>(L, ADt);
    gemm3_kernel<<<dim3(3, 6, 64), 256, 0, stream>>>(Dt, AQt, M4);
    gemm4_kernel<<<dim3(12, 3, 64), 256, 0, stream>>>(ADt, M4, out);
}